// Round 10
// baseline (105.230 us; speedup 1.0000x reference)
//
#include <hip/hip_runtime.h>

#define SS 4096
#define DD 1024
#define HH 16

typedef float nfloat4 __attribute__((ext_vector_type(4)));
typedef __attribute__((ext_vector_type(8))) short bf16x8;
typedef __attribute__((ext_vector_type(4))) float f32x4;

__device__ __forceinline__ short f2bf(float f) {
  union { float f; unsigned u; } z; z.f = f;
  return (short)((z.u + 0x8000u) >> 16);    // round-half-up to bf16
}

// ---------------------------------------------------------------------------
// K0: pre-pack wq,wk into MFMA A-fragment order, bf16.
// wf[m][t][lane][e] = w_m[t*32 + (lane>>4)*8 + e][lane&15]
// ---------------------------------------------------------------------------
__global__ __launch_bounds__(256) void k_wfrag(
    const float* __restrict__ wq, const float* __restrict__ wk,
    short* __restrict__ wf)
{
  const int m = blockIdx.x;                 // 0=q, 1=k
  const float* __restrict__ w = m ? wk : wq;
  short* __restrict__ dst = wf + m * 16384;
  for (int p = threadIdx.x; p < 2048; p += 256) {   // p = t*64 + lane
    const int t = p >> 6, l = p & 63;
    const int kbase = t*32 + ((l >> 4) * 8), col = l & 15;
    short v[8];
#pragma unroll
    for (int e = 0; e < 8; ++e)
      v[e] = f2bf(w[(size_t)(kbase + e)*HH + col]);
    short* o = dst + (size_t)p * 8;
#pragma unroll
    for (int e = 0; e < 8; ++e) o[e] = v[e];
  }
}

// ---------------------------------------------------------------------------
// K1: qh/kh via MFMA 16x16x32 bf16, staged through LDS by global_load_lds
// DMA (zero VGPR cost -> compiler CANNOT sink the loads; 16 independent
// 1KB DMA instrs per wave = 16KB in flight/wave, ~128KB/CU). fp32 tile in
// LDS, pitch 1028 floats: b128 fragment reads hit the uniform 8-word/bank
// floor (starts 4r+8g mod 32 -> each bank exactly 8 accesses, no excess
// conflict). bf16 conversion in-register, MFMA math identical to R8.
// ---------------------------------------------------------------------------
__global__ __launch_bounds__(256, 2) void k_qhkh(
    const float* __restrict__ q, const float* __restrict__ k,
    const short* __restrict__ wf,
    const float* __restrict__ bq, const float* __restrict__ bk,
    float* __restrict__ qh, float* __restrict__ kh)
{
  const int t = threadIdx.x;
  const int wid = t >> 6, lane = t & 63;
  const bool isk = blockIdx.x >= 1024;
  const int t16 = blockIdx.x & 1023;
  const float* __restrict__ src = isk ? k : q;
  const short* __restrict__ wfm = wf + (isk ? 16384 : 0);
  const float* __restrict__ bias = isk ? bk : bq;
  float* __restrict__ dst = isk ? kh : qh;
  const int s0 = t16 * 16;                   // flat row over (B,S)

  __shared__ float smem[16 * 1028];          // 65,792 B; red[] aliases later

  // A-fragments first (L2-hot): their vmcnt wait is subsumed by the barrier.
  const short* __restrict__ wfw = wfm + (size_t)(wid*8*64 + lane) * 8;
  bf16x8 afrag[8];
#pragma unroll
  for (int tt = 0; tt < 8; ++tt)
    afrag[tt] = *(const bf16x8*)(wfw + (size_t)(tt*64) * 8);

  // Stage via DMA: wave wid covers rows 4*wid..4*wid+3, 4 segments each.
  // Per instr: 64 lanes x 16B contiguous global -> LDS base + lane*16.
  {
    const int r0 = wid * 4;
#pragma unroll
    for (int rr = 0; rr < 4; ++rr) {
      const int row = r0 + rr;
      const float* gsrc = src + (size_t)(s0 + row)*DD + lane*4;
      float* lbase = smem + row*1028;
#pragma unroll
      for (int qd = 0; qd < 4; ++qd) {
        __builtin_amdgcn_global_load_lds(
            (const __attribute__((address_space(1))) void*)(gsrc + qd*256),
            (__attribute__((address_space(3))) void*)(lbase + qd*256),
            16, 0, 0);
      }
    }
  }
  __syncthreads();   // emits s_waitcnt vmcnt(0) + barrier: tile ready

  // MFMA: wave wid covers K in [wid*256,(wid+1)*256) = 8 steps.
  const int row = lane & 15, g = lane >> 4;
  const float* __restrict__ xrow = smem + row*1028 + wid*256 + g*8;
  f32x4 acc = {0.f, 0.f, 0.f, 0.f};
#pragma unroll
  for (int tt = 0; tt < 8; ++tt) {
    const float4 lo = *(const float4*)(xrow + tt*32);
    const float4 hi = *(const float4*)(xrow + tt*32 + 4);
    bf16x8 bb;
    bb[0]=f2bf(lo.x); bb[1]=f2bf(lo.y); bb[2]=f2bf(lo.z); bb[3]=f2bf(lo.w);
    bb[4]=f2bf(hi.x); bb[5]=f2bf(hi.y); bb[6]=f2bf(hi.z); bb[7]=f2bf(hi.w);
    acc = __builtin_amdgcn_mfma_f32_16x16x32_bf16(afrag[tt], bb, acc, 0, 0, 0);
  }
  __syncthreads();                           // tile reads done; alias as red
  float* red = smem;                         // [4][64][4]
  *(f32x4*)&red[(wid*64 + lane)*4] = acc;
  __syncthreads();                           // partials ready
  const int orow = t >> 4, ohead = t & 15;
  const int lane2 = ((ohead >> 2) << 4) + orow;
  const int j = ohead & 3;
  const float sacc = red[0*256 + lane2*4 + j] + red[1*256 + lane2*4 + j]
                   + red[2*256 + lane2*4 + j] + red[3*256 + lane2*4 + j];
  const float val = sacc + bias[ohead];
  dst[(size_t)(s0 + orow)*HH + ohead] = 1.f/(1.f + __expf(-val));
}

// ---------------------------------------------------------------------------
// K2: kvT partials.  Grid (32 schunk, 8 dchunk, 4 b) = 1024 blocks, 128
// rows/block. Thread (c = t&31 -> 4 d's, hh2 = (t>>5)&1 -> head half,
// g = t>>6 -> row group). Row mapping s = (jj*4+g)*32 + schunk.
// ---------------------------------------------------------------------------
__global__ __launch_bounds__(256, 8) void k_kvt(
    const float* __restrict__ v, const float* __restrict__ kh,
    float* __restrict__ part)
{
  const int schunk = blockIdx.x;   // 0..31
  const int dchunk = blockIdx.y;   // 0..7
  const int b = blockIdx.z;
  const int t = threadIdx.x;
  const int c = t & 31;
  const int hh2 = (t >> 5) & 1;
  const int g = t >> 6;            // 0..3
  const int d0 = dchunk*128 + c*4;
  float acc[8][4];
#pragma unroll
  for (int h = 0; h < 8; ++h) {
    acc[h][0] = 0.f; acc[h][1] = 0.f; acc[h][2] = 0.f; acc[h][3] = 0.f;
  }
#pragma unroll 2
  for (int jj = 0; jj < 32; ++jj) {
    const int s = (jj*4 + g)*32 + schunk;
    const size_t rb = (size_t)(b*SS + s);
    const float4 v4 = *(const float4*)(v + rb*DD + d0);
    const float4* khp = (const float4*)(kh + rb*HH) + hh2*2;
    const float4 k0 = khp[0], k1 = khp[1];
    const float kk[8] = {k0.x,k0.y,k0.z,k0.w, k1.x,k1.y,k1.z,k1.w};
#pragma unroll
    for (int h = 0; h < 8; ++h) {
      acc[h][0] = fmaf(kk[h], v4.x, acc[h][0]);
      acc[h][1] = fmaf(kk[h], v4.y, acc[h][1]);
      acc[h][2] = fmaf(kk[h], v4.z, acc[h][2]);
      acc[h][3] = fmaf(kk[h], v4.w, acc[h][3]);
    }
  }
  __shared__ float lds[4][2][128];
  const size_t pbase = (size_t)((b*8 + dchunk)*32 + schunk) * 2048;
#pragma unroll   // full unroll: acc indices stay compile-time
  for (int h = 0; h < 8; ++h) {
    *(float4*)&lds[g][hh2][c*4] =
        make_float4(acc[h][0], acc[h][1], acc[h][2], acc[h][3]);
    __syncthreads();
    {
      const int hh2r = t >> 7, dl = t & 127;
      const float sum = lds[0][hh2r][dl] + lds[1][hh2r][dl]
                      + lds[2][hh2r][dl] + lds[3][hh2r][dl];
      part[pbase + (hh2r*8 + h)*128 + dl] = sum;
    }
    __syncthreads();
  }
}

// ---------------------------------------------------------------------------
// K3: reduce part over the 32 schunks -> kvt[b][h][1024].
// Grid (8 dchunk, 4 b, 4 head-quarter), fully coalesced reads.
// ---------------------------------------------------------------------------
__global__ __launch_bounds__(256, 8) void k_red(
    const float* __restrict__ part, float* __restrict__ kvt)
{
  const int dchunk = blockIdx.x;
  const int b = blockIdx.y;
  const int hq = blockIdx.z;       // 0..3
  const int t = threadIdx.x;
  const size_t pb = (size_t)((b*8 + dchunk)*32) * 2048;
#pragma unroll
  for (int ho = 0; ho < 2; ++ho) {
    const int h = hq*4 + ho*2 + (t >> 7), dl = t & 127;
    float s = 0.f;
#pragma unroll 8
    for (int sc = 0; sc < 32; ++sc)
      s += part[pb + (size_t)sc*2048 + h*128 + dl];
    kvt[(size_t)(b*16 + h)*1024 + dchunk*128 + dl] = s;
  }
}

// ---------------------------------------------------------------------------
// K4: per (b,h): kv[b,h,dv] = sum_d kvt[b,h,d]*wv[d, h*64+dv] + ksum*bv,
// ksum = sum_s kh[b,s,h] computed in-block.
// ---------------------------------------------------------------------------
__global__ __launch_bounds__(256, 2) void k_kv(
    const float* __restrict__ kvt, const float* __restrict__ kh,
    const float* __restrict__ wv, const float* __restrict__ bv,
    float* __restrict__ kv)
{
  const int h = blockIdx.x;    // 0..15
  const int b = blockIdx.y;
  const int t = threadIdx.x;
  const int dg = t >> 6, c = t & 63;
  const float* kp = kvt + (size_t)(b*16 + h)*1024 + dg*256;
  const float* wp = wv + (size_t)(dg*256)*DD + h*64 + c;
  float p = 0.f;
#pragma unroll 4
  for (int dd = 0; dd < 256; ++dd)
    p = fmaf(kp[dd], wp[(size_t)dd*DD], p);
  float ks = 0.f;
#pragma unroll 4
  for (int m = 0; m < 16; ++m)
    ks += kh[(size_t)(b*SS + m*256 + t)*HH + h];
  __shared__ float red[256], redk[256];
  red[t] = p; redk[t] = ks;
  __syncthreads();
  if (t < 128) redk[t] += redk[t + 128];
  __syncthreads();
  if (t < 64) redk[t] += redk[t + 64];
  __syncthreads();
  if (t < 64) {
    float kst = redk[t];
#pragma unroll
    for (int off = 32; off > 0; off >>= 1) kst += __shfl_xor(kst, off);
    const float psum = red[t] + red[64+t] + red[128+t] + red[192+t];
    kv[(size_t)b*1024 + h*64 + t] = psum + kst * bv[h*64 + t];
  }
}

// ---------------------------------------------------------------------------
// K5: per (b,h): state = cumsum_h kv (HEAD-axis cumsum), then
// W2[b,h,d] = sum_dv state[dv] * wo[(h*64+dv), d]
// ---------------------------------------------------------------------------
__global__ __launch_bounds__(256) void k_w2(
    const float* __restrict__ kv, const float* __restrict__ wo,
    float* __restrict__ W2)
{
  const int bh = blockIdx.x;
  const int b = bh >> 4, h = bh & 15;
  const int t = threadIdx.x;
  __shared__ float st[64];
  if (t < 64) {
    float s = 0.f;
    for (int hp = 0; hp <= h; ++hp) s += kv[(size_t)b*1024 + hp*64 + t];
    st[t] = s;
  }
  __syncthreads();
  const int d0 = t * 4;
  float4 acc = {0.f, 0.f, 0.f, 0.f};
#pragma unroll 4
  for (int dv = 0; dv < 64; ++dv) {
    const float sv = st[dv];
    const float4 w4 = *(const float4*)(wo + (size_t)(h*64 + dv)*DD + d0);
    acc.x = fmaf(sv, w4.x, acc.x);
    acc.y = fmaf(sv, w4.y, acc.y);
    acc.z = fmaf(sv, w4.z, acc.z);
    acc.w = fmaf(sv, w4.w, acc.w);
  }
  *(float4*)(W2 + (size_t)(b*HH + h)*DD + d0) = acc;
}

// ---------------------------------------------------------------------------
// K6: out[b,s,:] = bo + sum_h qh[b,s,h] * W2[b,h,:]
// 2048 blocks x 8 rows; s = r*512 + bx -> 512 consecutive rows concurrent.
// Nontemporal stores.
// ---------------------------------------------------------------------------
__global__ __launch_bounds__(256, 4) void k_out(
    const float* __restrict__ qh, const float* __restrict__ W2,
    const float* __restrict__ bo, float* __restrict__ out)
{
  const int bx = blockIdx.x;   // 0..511
  const int b = blockIdx.y;
  const int t = threadIdx.x;
  const int d0 = t * 4;
  float4 w2[16];
#pragma unroll
  for (int h = 0; h < 16; ++h)
    w2[h] = *(const float4*)(W2 + (size_t)(b*HH + h)*DD + d0);
  const float4 bo4 = *(const float4*)(bo + d0);
  __shared__ float qs[128];
  if (t < 128)
    qs[t] = qh[(size_t)(b*SS + (t>>4)*512 + bx)*HH + (t & 15)];
  __syncthreads();
#pragma unroll
  for (int r = 0; r < 8; ++r) {
    const float4* qr = (const float4*)(qs + r*16);
    const float4 q0 = qr[0], q1 = qr[1], q2 = qr[2], q3 = qr[3];
    const float qv[16] = {q0.x,q0.y,q0.z,q0.w, q1.x,q1.y,q1.z,q1.w,
                          q2.x,q2.y,q2.z,q2.w, q3.x,q3.y,q3.z,q3.w};
    float4 o = bo4;
#pragma unroll
    for (int h = 0; h < 16; ++h) {
      o.x = fmaf(qv[h], w2[h].x, o.x);
      o.y = fmaf(qv[h], w2[h].y, o.y);
      o.z = fmaf(qv[h], w2[h].z, o.z);
      o.w = fmaf(qv[h], w2[h].w, o.w);
    }
    nfloat4 ov = { o.x, o.y, o.z, o.w };
    nfloat4* dst = (nfloat4*)(out + (size_t)(b*SS + r*512 + bx)*DD + d0);
    __builtin_nontemporal_store(ov, dst);
  }
}

// ---------------------------------------------------------------------------
extern "C" void kernel_launch(void* const* d_in, const int* in_sizes, int n_in,
                              void* d_out, int out_size, void* d_ws, size_t ws_size,
                              hipStream_t stream)
{
  const float* q  = (const float*)d_in[0];
  const float* k  = (const float*)d_in[1];
  const float* v  = (const float*)d_in[2];
  const float* wq = (const float*)d_in[3];
  const float* bq = (const float*)d_in[4];
  const float* wk = (const float*)d_in[5];
  const float* bk = (const float*)d_in[6];
  const float* wv = (const float*)d_in[7];
  const float* bv = (const float*)d_in[8];
  const float* wo = (const float*)d_in[9];
  const float* bo = (const float*)d_in[10];
  float* out = (float*)d_out;
  float* ws  = (float*)d_ws;

  // ws layout (floats): qh 262144 | kh 262144 | kvt 65536 | kv 4096 | W2 65536
  float* qh  = ws;
  float* kh  = ws + 262144;
  float* kvt = ws + 524288;
  float* kv  = ws + 589824;
  float* W2  = ws + 593920;
  // d_out scratch: kvT partials (1024 blocks * 2048 floats = 8 MB) at the
  // front; wf (weight fragments, 64KB) at +16MB. Both consumed before k_out
  // fully overwrites d_out.
  float* part = out;
  short* wf   = (short*)(out + 4194304);

  hipLaunchKernelGGL(k_wfrag, dim3(2), dim3(256), 0, stream,
                     wq, wk, wf);
  hipLaunchKernelGGL(k_qhkh, dim3(2048), dim3(256), 0, stream,
                     q, k, wf, bq, bk, qh, kh);
  hipLaunchKernelGGL(k_kvt, dim3(32, 8, 4), dim3(256), 0, stream,
                     v, kh, part);
  hipLaunchKernelGGL(k_red, dim3(8, 4, 4), dim3(256), 0, stream,
                     part, kvt);
  hipLaunchKernelGGL(k_kv, dim3(16, 4), dim3(256), 0, stream,
                     kvt, kh, wv, bv, kv);
  hipLaunchKernelGGL(k_w2, dim3(64), dim3(256), 0, stream,
                     kv, wo, W2);
  hipLaunchKernelGGL(k_out, dim3(512, 4), dim3(256), 0, stream,
                     qh, W2, bo, out);
}

// Round 11
// 100.768 us; speedup vs baseline: 1.0443x; 1.0443x over previous
//
#include <hip/hip_runtime.h>

#define SS 4096
#define DD 1024
#define HH 16

typedef float nfloat4 __attribute__((ext_vector_type(4)));
typedef __attribute__((ext_vector_type(8))) short bf16x8;
typedef __attribute__((ext_vector_type(4))) float f32x4;

__device__ __forceinline__ short f2bf(float f) {
  union { float f; unsigned u; } z; z.f = f;
  return (short)((z.u + 0x8000u) >> 16);    // round-half-up to bf16
}

// ---------------------------------------------------------------------------
// K0: pre-pack wq,wk into MFMA A-fragment order, bf16.
// wf[m][t][lane][e] = w_m[t*32 + (lane>>4)*8 + e][lane&15]   (m: 0=q, 1=k)
// ---------------------------------------------------------------------------
__global__ __launch_bounds__(256) void k_wfrag(
    const float* __restrict__ wq, const float* __restrict__ wk,
    short* __restrict__ wf)
{
  const int m = blockIdx.x;
  const float* __restrict__ w = m ? wk : wq;
  short* __restrict__ dst = wf + m * 16384;
  for (int p = threadIdx.x; p < 2048; p += 256) {   // p = t*64 + lane
    const int t = p >> 6, l = p & 63;
    const int kbase = t*32 + ((l >> 4) * 8), col = l & 15;
    short v[8];
#pragma unroll
    for (int e = 0; e < 8; ++e)
      v[e] = f2bf(w[(size_t)(kbase + e)*HH + col]);
    short* o = dst + (size_t)p * 8;
#pragma unroll
    for (int e = 0; e < 8; ++e) o[e] = v[e];
  }
}

// ---------------------------------------------------------------------------
// K1: kh = sigmoid(k@wk+bk) via MFMA 16x16x32 bf16, DMA-staged (R10 proven
// structure, k-side only). 1024 blocks, one 16-row tile each.
// ---------------------------------------------------------------------------
__global__ __launch_bounds__(256, 2) void k_kh(
    const float* __restrict__ k, const short* __restrict__ wf,
    const float* __restrict__ bk, float* __restrict__ kh)
{
  const int t = threadIdx.x;
  const int wid = t >> 6, lane = t & 63;
  const int s0 = blockIdx.x * 16;            // flat row over (B,S)
  const short* __restrict__ wfm = wf + 16384;   // k-half

  __shared__ float smem[16 * 1028];          // 65,792 B; red[] aliases later

  const short* __restrict__ wfw = wfm + (size_t)(wid*8*64 + lane) * 8;
  bf16x8 afrag[8];
#pragma unroll
  for (int tt = 0; tt < 8; ++tt)
    afrag[tt] = *(const bf16x8*)(wfw + (size_t)(tt*64) * 8);

  // DMA stage: wave wid rows 4*wid..4*wid+3, 4 x 1KB segments per row.
  {
    const int r0 = wid * 4;
#pragma unroll
    for (int rr = 0; rr < 4; ++rr) {
      const int row = r0 + rr;
      const float* gsrc = k + (size_t)(s0 + row)*DD + lane*4;
      float* lbase = smem + row*1028;
#pragma unroll
      for (int qd = 0; qd < 4; ++qd) {
        __builtin_amdgcn_global_load_lds(
            (const __attribute__((address_space(1))) void*)(gsrc + qd*256),
            (__attribute__((address_space(3))) void*)(lbase + qd*256),
            16, 0, 0);
      }
    }
  }
  __syncthreads();

  const int row = lane & 15, g = lane >> 4;
  const float* __restrict__ xrow = smem + row*1028 + wid*256 + g*8;
  f32x4 acc = {0.f, 0.f, 0.f, 0.f};
#pragma unroll
  for (int tt = 0; tt < 8; ++tt) {
    const float4 lo = *(const float4*)(xrow + tt*32);
    const float4 hi = *(const float4*)(xrow + tt*32 + 4);
    bf16x8 bb;
    bb[0]=f2bf(lo.x); bb[1]=f2bf(lo.y); bb[2]=f2bf(lo.z); bb[3]=f2bf(lo.w);
    bb[4]=f2bf(hi.x); bb[5]=f2bf(hi.y); bb[6]=f2bf(hi.z); bb[7]=f2bf(hi.w);
    acc = __builtin_amdgcn_mfma_f32_16x16x32_bf16(afrag[tt], bb, acc, 0, 0, 0);
  }
  __syncthreads();
  float* red = smem;                         // [4][64][4]
  *(f32x4*)&red[(wid*64 + lane)*4] = acc;
  __syncthreads();
  const int orow = t >> 4, ohead = t & 15;
  const int lane2 = ((ohead >> 2) << 4) + orow;
  const int j = ohead & 3;
  const float sacc = red[0*256 + lane2*4 + j] + red[1*256 + lane2*4 + j]
                   + red[2*256 + lane2*4 + j] + red[3*256 + lane2*4 + j];
  const float val = sacc + bk[ohead];
  kh[(size_t)(s0 + orow)*HH + ohead] = 1.f/(1.f + __expf(-val));
}

// ---------------------------------------------------------------------------
// K2: kvT partials (verbatim R10). Grid (32 schunk, 8 dchunk, 4 b).
// ---------------------------------------------------------------------------
__global__ __launch_bounds__(256, 8) void k_kvt(
    const float* __restrict__ v, const float* __restrict__ kh,
    float* __restrict__ part)
{
  const int schunk = blockIdx.x;   // 0..31
  const int dchunk = blockIdx.y;   // 0..7
  const int b = blockIdx.z;
  const int t = threadIdx.x;
  const int c = t & 31;
  const int hh2 = (t >> 5) & 1;
  const int g = t >> 6;            // 0..3
  const int d0 = dchunk*128 + c*4;
  float acc[8][4];
#pragma unroll
  for (int h = 0; h < 8; ++h) {
    acc[h][0] = 0.f; acc[h][1] = 0.f; acc[h][2] = 0.f; acc[h][3] = 0.f;
  }
#pragma unroll 2
  for (int jj = 0; jj < 32; ++jj) {
    const int s = (jj*4 + g)*32 + schunk;
    const size_t rb = (size_t)(b*SS + s);
    const float4 v4 = *(const float4*)(v + rb*DD + d0);
    const float4* khp = (const float4*)(kh + rb*HH) + hh2*2;
    const float4 k0 = khp[0], k1 = khp[1];
    const float kk[8] = {k0.x,k0.y,k0.z,k0.w, k1.x,k1.y,k1.z,k1.w};
#pragma unroll
    for (int h = 0; h < 8; ++h) {
      acc[h][0] = fmaf(kk[h], v4.x, acc[h][0]);
      acc[h][1] = fmaf(kk[h], v4.y, acc[h][1]);
      acc[h][2] = fmaf(kk[h], v4.z, acc[h][2]);
      acc[h][3] = fmaf(kk[h], v4.w, acc[h][3]);
    }
  }
  __shared__ float lds[4][2][128];
  const size_t pbase = (size_t)((b*8 + dchunk)*32 + schunk) * 2048;
#pragma unroll   // full unroll: acc indices stay compile-time
  for (int h = 0; h < 8; ++h) {
    *(float4*)&lds[g][hh2][c*4] =
        make_float4(acc[h][0], acc[h][1], acc[h][2], acc[h][3]);
    __syncthreads();
    {
      const int hh2r = t >> 7, dl = t & 127;
      const float sum = lds[0][hh2r][dl] + lds[1][hh2r][dl]
                      + lds[2][hh2r][dl] + lds[3][hh2r][dl];
      part[pbase + (hh2r*8 + h)*128 + dl] = sum;
    }
    __syncthreads();
  }
}

// ---------------------------------------------------------------------------
// K3: fused k_red + k_kv. Grid (16 h, 4 b). Reduce part over 32 schunks into
// LDS kvt[1024], ksum from kh, wv contraction + bias -> kv[b,h,64].
// ---------------------------------------------------------------------------
__global__ __launch_bounds__(256, 4) void k_redkv(
    const float* __restrict__ part, const float* __restrict__ kh,
    const float* __restrict__ wv, const float* __restrict__ bv,
    float* __restrict__ kv)
{
  const int h = blockIdx.x;    // 0..15
  const int b = blockIdx.y;
  const int t = threadIdx.x;
  __shared__ float kvt[1024];
  __shared__ float red[256], redk[256];
#pragma unroll
  for (int m = 0; m < 4; ++m) {
    const int d = m*256 + t;
    const int dchunk = d >> 7, dl = d & 127;
    const size_t base = (size_t)((b*8 + dchunk)*32)*2048 + h*128 + dl;
    float s = 0.f;
#pragma unroll 8
    for (int sc = 0; sc < 32; ++sc) s += part[base + (size_t)sc*2048];
    kvt[d] = s;
  }
  float ks = 0.f;
#pragma unroll 4
  for (int m = 0; m < 16; ++m)
    ks += kh[(size_t)(b*SS + m*256 + t)*HH + h];
  redk[t] = ks;
  __syncthreads();                 // kvt + redk ready
  if (t < 128) redk[t] += redk[t + 128];
  __syncthreads();
  if (t < 64) redk[t] += redk[t + 64];
  __syncthreads();
  const int dg = t >> 6, c = t & 63;
  const float* wp = wv + (size_t)(dg*256)*DD + h*64 + c;
  float p = 0.f;
#pragma unroll 4
  for (int dd = 0; dd < 256; ++dd)
    p = fmaf(kvt[dg*256 + dd], wp[(size_t)dd*DD], p);
  red[t] = p;
  __syncthreads();
  if (t < 64) {
    float kst = redk[t];
#pragma unroll
    for (int off = 32; off > 0; off >>= 1) kst += __shfl_xor(kst, off);
    const float psum = red[t] + red[64+t] + red[128+t] + red[192+t];
    kv[(size_t)b*1024 + h*64 + t] = psum + kst * bv[h*64 + t];
  }
}

// ---------------------------------------------------------------------------
// K4: per (b,h): state = cumsum_h kv (HEAD-axis cumsum), then
// W2[b,h,d] = sum_dv state[dv] * wo[(h*64+dv), d]   (verbatim)
// ---------------------------------------------------------------------------
__global__ __launch_bounds__(256) void k_w2(
    const float* __restrict__ kv, const float* __restrict__ wo,
    float* __restrict__ W2)
{
  const int bh = blockIdx.x;
  const int b = bh >> 4, h = bh & 15;
  const int t = threadIdx.x;
  __shared__ float st[64];
  if (t < 64) {
    float s = 0.f;
    for (int hp = 0; hp <= h; ++hp) s += kv[(size_t)b*1024 + hp*64 + t];
    st[t] = s;
  }
  __syncthreads();
  const int d0 = t * 4;
  float4 acc = {0.f, 0.f, 0.f, 0.f};
#pragma unroll 4
  for (int dv = 0; dv < 64; ++dv) {
    const float sv = st[dv];
    const float4 w4 = *(const float4*)(wo + (size_t)(h*64 + dv)*DD + d0);
    acc.x = fmaf(sv, w4.x, acc.x);
    acc.y = fmaf(sv, w4.y, acc.y);
    acc.z = fmaf(sv, w4.z, acc.z);
    acc.w = fmaf(sv, w4.w, acc.w);
  }
  *(float4*)(W2 + (size_t)(b*HH + h)*DD + d0) = acc;
}

// ---------------------------------------------------------------------------
// K5: FUSED q-projection + output. Per 16-row tile: DMA-stage q, MFMA ->
// qh tile (kept in LDS), then out[s,:] = bo + sum_h qh[s,h]*W2[b,h,:].
// Removes the qh global round-trip and one kernel launch entirely.
// ---------------------------------------------------------------------------
__global__ __launch_bounds__(256, 2) void k_qout(
    const float* __restrict__ q, const short* __restrict__ wf,
    const float* __restrict__ bq, const float* __restrict__ W2,
    const float* __restrict__ bo, float* __restrict__ out)
{
  const int t = threadIdx.x;
  const int wid = t >> 6, lane = t & 63;
  const int tile = blockIdx.x;               // 0..1023
  const int b = tile >> 8;                   // 256 tiles per batch
  const int s0 = tile * 16;

  __shared__ float smem[16 * 1028];          // tile; red aliases [0,1024); qs at [1024,1280)

  // Early loads (L2-hot), overlap with DMA: W2[b] slice + bo.
  float4 w2[16];
  {
    const float* w2p = W2 + (size_t)(b*HH)*DD + t*4;
#pragma unroll
    for (int h = 0; h < 16; ++h) w2[h] = *(const float4*)(w2p + h*DD);
  }
  const float4 bo4 = *(const float4*)(bo + t*4);

  const short* __restrict__ wfw = wf + (size_t)(wid*8*64 + lane) * 8;  // q-half
  bf16x8 afrag[8];
#pragma unroll
  for (int tt = 0; tt < 8; ++tt)
    afrag[tt] = *(const bf16x8*)(wfw + (size_t)(tt*64) * 8);

  // DMA stage q tile
  {
    const int r0 = wid * 4;
#pragma unroll
    for (int rr = 0; rr < 4; ++rr) {
      const int row = r0 + rr;
      const float* gsrc = q + (size_t)(s0 + row)*DD + lane*4;
      float* lbase = smem + row*1028;
#pragma unroll
      for (int qd = 0; qd < 4; ++qd) {
        __builtin_amdgcn_global_load_lds(
            (const __attribute__((address_space(1))) void*)(gsrc + qd*256),
            (__attribute__((address_space(3))) void*)(lbase + qd*256),
            16, 0, 0);
      }
    }
  }
  __syncthreads();

  // MFMA projection (K split across 4 waves)
  const int row = lane & 15, g = lane >> 4;
  const float* __restrict__ xrow = smem + row*1028 + wid*256 + g*8;
  f32x4 acc = {0.f, 0.f, 0.f, 0.f};
#pragma unroll
  for (int tt = 0; tt < 8; ++tt) {
    const float4 lo = *(const float4*)(xrow + tt*32);
    const float4 hi = *(const float4*)(xrow + tt*32 + 4);
    bf16x8 bb;
    bb[0]=f2bf(lo.x); bb[1]=f2bf(lo.y); bb[2]=f2bf(lo.z); bb[3]=f2bf(lo.w);
    bb[4]=f2bf(hi.x); bb[5]=f2bf(hi.y); bb[6]=f2bf(hi.z); bb[7]=f2bf(hi.w);
    acc = __builtin_amdgcn_mfma_f32_16x16x32_bf16(afrag[tt], bb, acc, 0, 0, 0);
  }
  __syncthreads();                           // tile reads done; alias as red
  float* red = smem;                         // [4][64][4]
  *(f32x4*)&red[(wid*64 + lane)*4] = acc;
  __syncthreads();
  {
    const int orow = t >> 4, ohead = t & 15;
    const int lane2 = ((ohead >> 2) << 4) + orow;
    const int j = ohead & 3;
    const float sacc = red[0*256 + lane2*4 + j] + red[1*256 + lane2*4 + j]
                     + red[2*256 + lane2*4 + j] + red[3*256 + lane2*4 + j];
    const float val = sacc + bq[ohead];
    smem[1024 + orow*16 + ohead] = 1.f/(1.f + __expf(-val));  // qs, disjoint from red
  }
  __syncthreads();

  // Output phase: thread owns cols [4t,4t+4) for all 16 rows.
  const float* qs = smem + 1024;
#pragma unroll
  for (int r = 0; r < 16; ++r) {
    float4 o = bo4;
#pragma unroll
    for (int h = 0; h < 16; ++h) {
      const float qv = qs[r*16 + h];         // LDS broadcast
      o.x = fmaf(qv, w2[h].x, o.x);
      o.y = fmaf(qv, w2[h].y, o.y);
      o.z = fmaf(qv, w2[h].z, o.z);
      o.w = fmaf(qv, w2[h].w, o.w);
    }
    nfloat4 ov = { o.x, o.y, o.z, o.w };
    nfloat4* dst = (nfloat4*)(out + (size_t)(s0 + r)*DD + t*4);
    __builtin_nontemporal_store(ov, dst);
  }
}

// ---------------------------------------------------------------------------
extern "C" void kernel_launch(void* const* d_in, const int* in_sizes, int n_in,
                              void* d_out, int out_size, void* d_ws, size_t ws_size,
                              hipStream_t stream)
{
  const float* q  = (const float*)d_in[0];
  const float* k  = (const float*)d_in[1];
  const float* v  = (const float*)d_in[2];
  const float* wq = (const float*)d_in[3];
  const float* bq = (const float*)d_in[4];
  const float* wk = (const float*)d_in[5];
  const float* bk = (const float*)d_in[6];
  const float* wv = (const float*)d_in[7];
  const float* bv = (const float*)d_in[8];
  const float* wo = (const float*)d_in[9];
  const float* bo = (const float*)d_in[10];
  float* out = (float*)d_out;
  float* ws  = (float*)d_ws;

  // ws layout (floats): kh 262144 | kv 4096 | W2 65536 | wf 16384 (32K shorts)
  float* kh = ws;
  float* kv = ws + 262144;
  float* W2 = ws + 266240;
  short* wf = (short*)(ws + 331776);
  // part (1024 blocks * 2048 floats = 8 MB) at the FRONT of d_out: consumed
  // by k_redkv, fully overwritten by k_qout afterwards.
  float* part = out;

  hipLaunchKernelGGL(k_wfrag, dim3(2), dim3(256), 0, stream,
                     wq, wk, wf);
  hipLaunchKernelGGL(k_kh, dim3(1024), dim3(256), 0, stream,
                     k, wf, bk, kh);
  hipLaunchKernelGGL(k_kvt, dim3(32, 8, 4), dim3(256), 0, stream,
                     v, kh, part);
  hipLaunchKernelGGL(k_redkv, dim3(16, 4), dim3(256), 0, stream,
                     part, kh, wv, bv, kv);
  hipLaunchKernelGGL(k_w2, dim3(64), dim3(256), 0, stream,
                     kv, wo, W2);
  hipLaunchKernelGGL(k_qout, dim3(1024), dim3(256), 0, stream,
                     q, wf, bq, W2, bo, out);
}

// Round 12
// 81.340 us; speedup vs baseline: 1.2937x; 1.2389x over previous
//
#include <hip/hip_runtime.h>

#define SS 4096
#define DD 1024
#define HH 16

typedef float nfloat4 __attribute__((ext_vector_type(4)));
typedef __attribute__((ext_vector_type(8))) short bf16x8;
typedef __attribute__((ext_vector_type(4))) float f32x4;

__device__ __forceinline__ short f2bf(float f) {
  union { float f; unsigned u; } z; z.f = f;
  return (short)((z.u + 0x8000u) >> 16);    // round-half-up to bf16
}

// ---------------------------------------------------------------------------
// K0: pre-pack wq,wk into MFMA A-fragment order, bf16.
// wf[m][t][lane][e] = w_m[t*32 + (lane>>4)*8 + e][lane&15]   (m: 0=q, 1=k)
// ---------------------------------------------------------------------------
__global__ __launch_bounds__(256) void k_wfrag(
    const float* __restrict__ wq, const float* __restrict__ wk,
    short* __restrict__ wf)
{
  const int m = blockIdx.x;
  const float* __restrict__ w = m ? wk : wq;
  short* __restrict__ dst = wf + m * 16384;
  for (int p = threadIdx.x; p < 2048; p += 256) {   // p = t*64 + lane
    const int t = p >> 6, l = p & 63;
    const int kbase = t*32 + ((l >> 4) * 8), col = l & 15;
    short v[8];
#pragma unroll
    for (int e = 0; e < 8; ++e)
      v[e] = f2bf(w[(size_t)(kbase + e)*HH + col]);
    short* o = dst + (size_t)p * 8;
#pragma unroll
    for (int e = 0; e < 8; ++e) o[e] = v[e];
  }
}

// ---------------------------------------------------------------------------
// K1: kh = sigmoid(k@wk+bk) via MFMA, DMA-staged (R10 structure) + NEW:
// per-tile head-sums ksp[tile][16] (feeds ksum reduction, kills the
// column-strided kh re-read that made k_redkv latency-bound).
// ---------------------------------------------------------------------------
__global__ __launch_bounds__(256, 2) void k_kh(
    const float* __restrict__ k, const short* __restrict__ wf,
    const float* __restrict__ bk, float* __restrict__ kh,
    float* __restrict__ ksp)
{
  const int t = threadIdx.x;
  const int wid = t >> 6, lane = t & 63;
  const int s0 = blockIdx.x * 16;            // flat row over (B,S)
  const short* __restrict__ wfm = wf + 16384;   // k-half

  __shared__ float smem[16 * 1028];          // 65,792 B; reused twice below

  const short* __restrict__ wfw = wfm + (size_t)(wid*8*64 + lane) * 8;
  bf16x8 afrag[8];
#pragma unroll
  for (int tt = 0; tt < 8; ++tt)
    afrag[tt] = *(const bf16x8*)(wfw + (size_t)(tt*64) * 8);

  // DMA stage: wave wid rows 4*wid..4*wid+3, 4 x 1KB segments per row.
  {
    const int r0 = wid * 4;
#pragma unroll
    for (int rr = 0; rr < 4; ++rr) {
      const int row = r0 + rr;
      const float* gsrc = k + (size_t)(s0 + row)*DD + lane*4;
      float* lbase = smem + row*1028;
#pragma unroll
      for (int qd = 0; qd < 4; ++qd) {
        __builtin_amdgcn_global_load_lds(
            (const __attribute__((address_space(1))) void*)(gsrc + qd*256),
            (__attribute__((address_space(3))) void*)(lbase + qd*256),
            16, 0, 0);
      }
    }
  }
  __syncthreads();

  const int row = lane & 15, g = lane >> 4;
  const float* __restrict__ xrow = smem + row*1028 + wid*256 + g*8;
  f32x4 acc = {0.f, 0.f, 0.f, 0.f};
#pragma unroll
  for (int tt = 0; tt < 8; ++tt) {
    const float4 lo = *(const float4*)(xrow + tt*32);
    const float4 hi = *(const float4*)(xrow + tt*32 + 4);
    bf16x8 bb;
    bb[0]=f2bf(lo.x); bb[1]=f2bf(lo.y); bb[2]=f2bf(lo.z); bb[3]=f2bf(lo.w);
    bb[4]=f2bf(hi.x); bb[5]=f2bf(hi.y); bb[6]=f2bf(hi.z); bb[7]=f2bf(hi.w);
    acc = __builtin_amdgcn_mfma_f32_16x16x32_bf16(afrag[tt], bb, acc, 0, 0, 0);
  }
  __syncthreads();
  float* red = smem;                         // [4][64][4]
  *(f32x4*)&red[(wid*64 + lane)*4] = acc;
  __syncthreads();
  const int orow = t >> 4, ohead = t & 15;
  const int lane2 = ((ohead >> 2) << 4) + orow;
  const int j = ohead & 3;
  const float sacc = red[0*256 + lane2*4 + j] + red[1*256 + lane2*4 + j]
                   + red[2*256 + lane2*4 + j] + red[3*256 + lane2*4 + j];
  const float sig = 1.f/(1.f + __expf(-(sacc + bk[ohead])));
  kh[(size_t)(s0 + orow)*HH + ohead] = sig;
  // per-tile head sums
  __syncthreads();                           // red reads done
  smem[t] = sig;
  __syncthreads();
  if (t < 16) {
    float s = 0.f;
#pragma unroll
    for (int r = 0; r < 16; ++r) s += smem[r*16 + t];
    ksp[blockIdx.x*16 + t] = s;
  }
}

// ---------------------------------------------------------------------------
// K2: kvT partials (verbatim R10). Grid (32 schunk, 8 dchunk, 4 b).
// ---------------------------------------------------------------------------
__global__ __launch_bounds__(256, 8) void k_kvt(
    const float* __restrict__ v, const float* __restrict__ kh,
    float* __restrict__ part)
{
  const int schunk = blockIdx.x;   // 0..31
  const int dchunk = blockIdx.y;   // 0..7
  const int b = blockIdx.z;
  const int t = threadIdx.x;
  const int c = t & 31;
  const int hh2 = (t >> 5) & 1;
  const int g = t >> 6;            // 0..3
  const int d0 = dchunk*128 + c*4;
  float acc[8][4];
#pragma unroll
  for (int h = 0; h < 8; ++h) {
    acc[h][0] = 0.f; acc[h][1] = 0.f; acc[h][2] = 0.f; acc[h][3] = 0.f;
  }
#pragma unroll 2
  for (int jj = 0; jj < 32; ++jj) {
    const int s = (jj*4 + g)*32 + schunk;
    const size_t rb = (size_t)(b*SS + s);
    const float4 v4 = *(const float4*)(v + rb*DD + d0);
    const float4* khp = (const float4*)(kh + rb*HH) + hh2*2;
    const float4 k0 = khp[0], k1 = khp[1];
    const float kk[8] = {k0.x,k0.y,k0.z,k0.w, k1.x,k1.y,k1.z,k1.w};
#pragma unroll
    for (int h = 0; h < 8; ++h) {
      acc[h][0] = fmaf(kk[h], v4.x, acc[h][0]);
      acc[h][1] = fmaf(kk[h], v4.y, acc[h][1]);
      acc[h][2] = fmaf(kk[h], v4.z, acc[h][2]);
      acc[h][3] = fmaf(kk[h], v4.w, acc[h][3]);
    }
  }
  __shared__ float lds[4][2][128];
  const size_t pbase = (size_t)((b*8 + dchunk)*32 + schunk) * 2048;
#pragma unroll   // full unroll: acc indices stay compile-time
  for (int h = 0; h < 8; ++h) {
    *(float4*)&lds[g][hh2][c*4] =
        make_float4(acc[h][0], acc[h][1], acc[h][2], acc[h][3]);
    __syncthreads();
    {
      const int hh2r = t >> 7, dl = t & 127;
      const float sum = lds[0][hh2r][dl] + lds[1][hh2r][dl]
                      + lds[2][hh2r][dl] + lds[3][hh2r][dl];
      part[pbase + (hh2r*8 + h)*128 + dl] = sum;
    }
    __syncthreads();
  }
}

// ---------------------------------------------------------------------------
// K3: reduce part over 32 schunks -> kvt[b][h][1024]. 128 blocks, coalesced.
// ---------------------------------------------------------------------------
__global__ __launch_bounds__(256, 8) void k_red(
    const float* __restrict__ part, float* __restrict__ kvt)
{
  const int dchunk = blockIdx.x;
  const int b = blockIdx.y;
  const int hq = blockIdx.z;       // 0..3
  const int t = threadIdx.x;
  const size_t pb = (size_t)((b*8 + dchunk)*32) * 2048;
#pragma unroll
  for (int ho = 0; ho < 2; ++ho) {
    const int h = hq*4 + ho*2 + (t >> 7), dl = t & 127;
    float s = 0.f;
#pragma unroll 8
    for (int sc = 0; sc < 32; ++sc)
      s += part[pb + (size_t)sc*2048 + h*128 + dl];
    kvt[(size_t)(b*16 + h)*1024 + dchunk*128 + dl] = s;
  }
}

// ---------------------------------------------------------------------------
// K4: wv contraction, COALESCED + PARALLEL. Grid (16 h, 4 b, 4 dq) = 256
// blocks. Wave w covers d in [dq*256+w*64, +64); lane = output column dv.
// Per d: 256B contiguous wv read + LDS broadcast of kvt[d]. Partials -> kvp.
// ---------------------------------------------------------------------------
__global__ __launch_bounds__(256, 4) void k_kv(
    const float* __restrict__ kvt, const float* __restrict__ wv,
    float* __restrict__ kvp)
{
  const int h = blockIdx.x;    // 0..15
  const int b = blockIdx.y;    // 0..3
  const int dq = blockIdx.z;   // 0..3
  const int t = threadIdx.x;
  const int w = t >> 6, lane = t & 63;
  __shared__ float kvs[256];
  __shared__ float red[256];
  kvs[t] = kvt[(size_t)(b*16 + h)*1024 + dq*256 + t];
  __syncthreads();
  const float* __restrict__ wp = wv + (size_t)(dq*256 + w*64)*DD + h*64 + lane;
  float acc = 0.f;
#pragma unroll 16
  for (int i = 0; i < 64; ++i)
    acc = fmaf(kvs[w*64 + i], wp[(size_t)i*DD], acc);
  red[t] = acc;
  __syncthreads();
  if (t < 64)
    kvp[((size_t)(b*16 + h)*4 + dq)*64 + t] =
        red[t] + red[64+t] + red[128+t] + red[192+t];
}

// ---------------------------------------------------------------------------
// K5: finalize kv. Grid (4 b). ksum from ksp (one coalesced load/thread),
// kv[b][h*64+dv] = sum_dq kvp + ksum[h]*bv.
// ---------------------------------------------------------------------------
__global__ __launch_bounds__(256) void k_kvfin(
    const float* __restrict__ kvp, const float* __restrict__ ksp,
    const float* __restrict__ bv, float* __restrict__ kv)
{
  const int b = blockIdx.x;
  const int t = threadIdx.x;
  __shared__ float red[256];
  __shared__ float ksum[16];
  float s = 0.f;
#pragma unroll
  for (int m = 0; m < 16; ++m)
    s += ksp[b*4096 + m*256 + t];
  red[t] = s;
  __syncthreads();
  if (t < 16) {
    float ks = 0.f;
#pragma unroll
    for (int g = 0; g < 16; ++g) ks += red[g*16 + t];
    ksum[t] = ks;
  }
  __syncthreads();
#pragma unroll
  for (int j = 0; j < 4; ++j) {
    const int idx = j*256 + t;
    const int h = idx >> 6;
    const float* kp = kvp + (size_t)(b*16 + h)*256 + (idx & 63);
    kv[(size_t)b*1024 + idx] =
        kp[0] + kp[64] + kp[128] + kp[192] + ksum[h]*bv[idx];
  }
}

// ---------------------------------------------------------------------------
// K6: per (b,h): state = cumsum_h kv (HEAD-axis cumsum), then
// W2[b,h,d] = sum_dv state[dv] * wo[(h*64+dv), d]   (verbatim)
// ---------------------------------------------------------------------------
__global__ __launch_bounds__(256) void k_w2(
    const float* __restrict__ kv, const float* __restrict__ wo,
    float* __restrict__ W2)
{
  const int bh = blockIdx.x;
  const int b = bh >> 4, h = bh & 15;
  const int t = threadIdx.x;
  __shared__ float st[64];
  if (t < 64) {
    float s = 0.f;
    for (int hp = 0; hp <= h; ++hp) s += kv[(size_t)b*1024 + hp*64 + t];
    st[t] = s;
  }
  __syncthreads();
  const int d0 = t * 4;
  float4 acc = {0.f, 0.f, 0.f, 0.f};
#pragma unroll 4
  for (int dv = 0; dv < 64; ++dv) {
    const float sv = st[dv];
    const float4 w4 = *(const float4*)(wo + (size_t)(h*64 + dv)*DD + d0);
    acc.x = fmaf(sv, w4.x, acc.x);
    acc.y = fmaf(sv, w4.y, acc.y);
    acc.z = fmaf(sv, w4.z, acc.z);
    acc.w = fmaf(sv, w4.w, acc.w);
  }
  *(float4*)(W2 + (size_t)(b*HH + h)*DD + d0) = acc;
}

// ---------------------------------------------------------------------------
// K7: FUSED q-projection + output (verbatim R11). DMA-stage q, MFMA -> qh in
// LDS, out = bo + qh @ W2[b]. Nontemporal stores.
// ---------------------------------------------------------------------------
__global__ __launch_bounds__(256, 2) void k_qout(
    const float* __restrict__ q, const short* __restrict__ wf,
    const float* __restrict__ bq, const float* __restrict__ W2,
    const float* __restrict__ bo, float* __restrict__ out)
{
  const int t = threadIdx.x;
  const int wid = t >> 6, lane = t & 63;
  const int tile = blockIdx.x;               // 0..1023
  const int b = tile >> 8;                   // 256 tiles per batch
  const int s0 = tile * 16;

  __shared__ float smem[16 * 1028];

  float4 w2[16];
  {
    const float* w2p = W2 + (size_t)(b*HH)*DD + t*4;
#pragma unroll
    for (int h = 0; h < 16; ++h) w2[h] = *(const float4*)(w2p + h*DD);
  }
  const float4 bo4 = *(const float4*)(bo + t*4);

  const short* __restrict__ wfw = wf + (size_t)(wid*8*64 + lane) * 8;  // q-half
  bf16x8 afrag[8];
#pragma unroll
  for (int tt = 0; tt < 8; ++tt)
    afrag[tt] = *(const bf16x8*)(wfw + (size_t)(tt*64) * 8);

  {
    const int r0 = wid * 4;
#pragma unroll
    for (int rr = 0; rr < 4; ++rr) {
      const int row = r0 + rr;
      const float* gsrc = q + (size_t)(s0 + row)*DD + lane*4;
      float* lbase = smem + row*1028;
#pragma unroll
      for (int qd = 0; qd < 4; ++qd) {
        __builtin_amdgcn_global_load_lds(
            (const __attribute__((address_space(1))) void*)(gsrc + qd*256),
            (__attribute__((address_space(3))) void*)(lbase + qd*256),
            16, 0, 0);
      }
    }
  }
  __syncthreads();

  const int row = lane & 15, g = lane >> 4;
  const float* __restrict__ xrow = smem + row*1028 + wid*256 + g*8;
  f32x4 acc = {0.f, 0.f, 0.f, 0.f};
#pragma unroll
  for (int tt = 0; tt < 8; ++tt) {
    const float4 lo = *(const float4*)(xrow + tt*32);
    const float4 hi = *(const float4*)(xrow + tt*32 + 4);
    bf16x8 bb;
    bb[0]=f2bf(lo.x); bb[1]=f2bf(lo.y); bb[2]=f2bf(lo.z); bb[3]=f2bf(lo.w);
    bb[4]=f2bf(hi.x); bb[5]=f2bf(hi.y); bb[6]=f2bf(hi.z); bb[7]=f2bf(hi.w);
    acc = __builtin_amdgcn_mfma_f32_16x16x32_bf16(afrag[tt], bb, acc, 0, 0, 0);
  }
  __syncthreads();
  float* red = smem;                         // [4][64][4]
  *(f32x4*)&red[(wid*64 + lane)*4] = acc;
  __syncthreads();
  {
    const int orow = t >> 4, ohead = t & 15;
    const int lane2 = ((ohead >> 2) << 4) + orow;
    const int j = ohead & 3;
    const float sacc = red[0*256 + lane2*4 + j] + red[1*256 + lane2*4 + j]
                     + red[2*256 + lane2*4 + j] + red[3*256 + lane2*4 + j];
    const float val = sacc + bq[ohead];
    smem[1024 + orow*16 + ohead] = 1.f/(1.f + __expf(-val));
  }
  __syncthreads();

  const float* qs = smem + 1024;
#pragma unroll
  for (int r = 0; r < 16; ++r) {
    float4 o = bo4;
#pragma unroll
    for (int h = 0; h < 16; ++h) {
      const float qv = qs[r*16 + h];
      o.x = fmaf(qv, w2[h].x, o.x);
      o.y = fmaf(qv, w2[h].y, o.y);
      o.z = fmaf(qv, w2[h].z, o.z);
      o.w = fmaf(qv, w2[h].w, o.w);
    }
    nfloat4 ov = { o.x, o.y, o.z, o.w };
    nfloat4* dst = (nfloat4*)(out + (size_t)(s0 + r)*DD + t*4);
    __builtin_nontemporal_store(ov, dst);
  }
}

// ---------------------------------------------------------------------------
extern "C" void kernel_launch(void* const* d_in, const int* in_sizes, int n_in,
                              void* d_out, int out_size, void* d_ws, size_t ws_size,
                              hipStream_t stream)
{
  const float* q  = (const float*)d_in[0];
  const float* k  = (const float*)d_in[1];
  const float* v  = (const float*)d_in[2];
  const float* wq = (const float*)d_in[3];
  const float* bq = (const float*)d_in[4];
  const float* wk = (const float*)d_in[5];
  const float* bk = (const float*)d_in[6];
  const float* wv = (const float*)d_in[7];
  const float* bv = (const float*)d_in[8];
  const float* wo = (const float*)d_in[9];
  const float* bo = (const float*)d_in[10];
  float* out = (float*)d_out;
  float* ws  = (float*)d_ws;

  // ws layout (floats):
  // kh 262144 | kvt 65536 | kvp 16384 | ksp 16384 | kv 4096 | W2 65536 | wf
  float* kh  = ws;
  float* kvt = ws + 262144;
  float* kvp = ws + 327680;
  float* ksp = ws + 344064;
  float* kv  = ws + 360448;
  float* W2  = ws + 364544;
  short* wf  = (short*)(ws + 430080);
  // part (8 MB) at the FRONT of d_out: consumed by k_red, fully overwritten
  // by k_qout afterwards.
  float* part = out;

  hipLaunchKernelGGL(k_wfrag, dim3(2), dim3(256), 0, stream,
                     wq, wk, wf);
  hipLaunchKernelGGL(k_kh, dim3(1024), dim3(256), 0, stream,
                     k, wf, bk, kh, ksp);
  hipLaunchKernelGGL(k_kvt, dim3(32, 8, 4), dim3(256), 0, stream,
                     v, kh, part);
  hipLaunchKernelGGL(k_red, dim3(8, 4, 4), dim3(256), 0, stream,
                     part, kvt);
  hipLaunchKernelGGL(k_kv, dim3(16, 4, 4), dim3(256), 0, stream,
                     kvt, wv, kvp);
  hipLaunchKernelGGL(k_kvfin, dim3(4), dim3(256), 0, stream,
                     kvp, ksp, bv, kv);
  hipLaunchKernelGGL(k_w2, dim3(64), dim3(256), 0, stream,
                     kv, wo, W2);
  hipLaunchKernelGGL(k_qout, dim3(1024), dim3(256), 0, stream,
                     q, wf, bq, W2, bo, out);
}